// Round 10
// baseline (6781.110 us; speedup 1.0000x reference)
//
#include <hip/hip_runtime.h>
#include <cmath>

// Problem constants: B=256, T=256, D=128, E=32, F1=F2=512
#define B_   256
#define T_   256
#define D_   128
#define E_   32
#define F_   512
#define RPB  16             // rows per block (16 independent blocks, zero inter-block traffic)
#define WR   4              // W2 ksteps resident in registers; 16-WR streamed from ws
#define ALPHA_F 0.1f
#define SCALE_F 0.31622776601683794f   // sqrt(0.1)

typedef float f32x4 __attribute__((ext_vector_type(4)));
typedef short s16x8 __attribute__((ext_vector_type(8)));
#define MFMA __builtin_amdgcn_mfma_f32_16x16x32_bf16

// ---- bf16 helpers (RNE) ----
__device__ __forceinline__ unsigned short f2bf(float f) {
    unsigned u = __float_as_uint(f);
    return (unsigned short)((u + 0x7FFFu + ((u >> 16) & 1u)) >> 16);
}
__device__ __forceinline__ unsigned pack2(float lo, float hi) {
    return (unsigned)f2bf(lo) | ((unsigned)f2bf(hi) << 16);
}

// A-fragment from 8 consecutive f32 (carry / ext rows)
__device__ __forceinline__ s16x8 frag_from_f32(const float* p) {
    float4 a = *(const float4*)p;
    float4 b = *(const float4*)(p + 4);
    union { unsigned q[4]; s16x8 v; } u;
    u.q[0] = pack2(a.x, a.y); u.q[1] = pack2(a.z, a.w);
    u.q[2] = pack2(b.x, b.y); u.q[3] = pack2(b.z, b.w);
    return u.v;
}

// B-fragment built directly from an f32 weight matrix (init only):
// elem e = W[(k0+e)*ldw + c]  (k0 = 32s + 8*(l>>4), c = 16*tile + (l&15))
__device__ __forceinline__ s16x8 frag_from_W(const float* W, int ldw, int k0, int c) {
    union { unsigned q[4]; s16x8 v; } u;
#pragma unroll
    for (int e2 = 0; e2 < 4; e2++)
        u.q[e2] = pack2(W[(size_t)(k0 + 2 * e2) * ldw + c],
                        W[(size_t)(k0 + 2 * e2 + 1) * ldw + c]);
    return u.v;
}

// Streamed W2 frag from the pre-converted ws image (plain cached load, L2-resident)
__device__ __forceinline__ s16x8 ld_ws_frag(const unsigned* fb, int tl, int s, int l) {
    union { uint4 q; s16x8 v; } u;
    u.q = *(const uint4*)(fb + (((unsigned)(tl * 16 + s) * 64 + l) << 2));
    return u.v;
}

// ================= kernel A: one-time W2 f32 -> bf16 frag image in ws =================
// frag f = tl*16 + s; u32 word layout: ws[(f*64 + l)*4 + piece]
__global__ void __launch_bounds__(256) w2_convert_kernel(const float* __restrict__ W2,
                                                         unsigned* __restrict__ ws) {
    int gid = blockIdx.x * 256 + threadIdx.x;   // 32768 threads = 512 frags x 64 lanes
    int f = gid >> 6, l = gid & 63;
    int tl = f >> 4, s = f & 15;
    int c = 16 * tl + (l & 15);
    uint4 o;
    unsigned q[4];
#pragma unroll
    for (int piece = 0; piece < 4; piece++) {
        int k = 32 * s + 8 * (l >> 4) + 2 * piece;
        q[piece] = pack2(W2[(size_t)k * F_ + c], W2[(size_t)(k + 1) * F_ + c]);
    }
    o.x = q[0]; o.y = q[1]; o.z = q[2]; o.w = q[3];
    *(uint4*)(ws + ((size_t)gid << 2)) = o;
}

// ================= kernel B: the scan (one CU per 16 rows, no inter-block traffic) =================
__global__ void __launch_bounds__(256, 1)
sde_scan_kernel(const float* __restrict__ carry, const float* __restrict__ x,
                const float* __restrict__ ext,   const float* __restrict__ noise,
                const float* __restrict__ W1,    const float* __restrict__ b1,
                const float* __restrict__ W2,    const float* __restrict__ b2,
                const float* __restrict__ W3,    const float* __restrict__ b3,
                float* __restrict__ out,         const unsigned* __restrict__ wsW2) {
    __shared__ alignas(16) short    W3f[8 * 16 * 64 * 8];  // 128 KB: W3 B-frags [tile][s][lane][e]
    __shared__ alignas(16) unsigned hx[16 * 64 * 4];       // 16 KB: h1 then h2, A-frag layout
    __shared__ alignas(16) unsigned yx[4 * 64 * 4];        // 4 KB: y A-frags
    __shared__ float b1s[F_], b2s[F_];                     // 4 KB

    const int tid = threadIdx.x;
    const int rb  = blockIdx.x * RPB;    // this block's batch-row base
    const int w  = tid >> 6;             // wave 0..3
    const int l  = tid & 63;
    const int lr = l & 15;
    const int lh = l >> 4;
    const short* hxs = (const short*)hx;
    const short* yxs = (const short*)yx;

    float* yfin  = out;
    float* ys_o  = out + B_ * D_;
    float* mup_o = ys_o  + (size_t)B_ * T_ * D_;
    float* mus_o = mup_o + (size_t)B_ * T_ * D_;
    float* std_o = mus_o + (size_t)B_ * T_ * D_;

    // ---- init: W3 -> LDS frags (layout proven in R9) ----
    for (int e4 = tid; e4 < 512 * 32; e4 += 256) {
        int k = e4 >> 5, c0 = (e4 & 31) << 2;
        float4 v = *(const float4*)(W3 + (size_t)k * D_ + c0);
        float vv[4] = {v.x, v.y, v.z, v.w};
#pragma unroll
        for (int m = 0; m < 4; m++) {
            int c = c0 + m;
            W3f[(((c >> 4) * 16 + (k >> 5)) * 64 + (c & 15) + 16 * ((k >> 3) & 3)) * 8 + (k & 7)] =
                (short)f2bf(vv[m]);
        }
    }
    for (int i = tid; i < F_; i += 256) { b1s[i] = b1[i]; b2s[i] = b2[i]; }

    // W1 -> registers (8 col-tiles x 5 ksteps per wave)
    s16x8 w1r[8][5];
#pragma unroll
    for (int p = 0; p < 8; p++)
#pragma unroll
        for (int s = 0; s < 5; s++)
            w1r[p][s] = frag_from_W(W1, F_, 32 * s + 8 * lh, 16 * (8 * w + p) + lr);
    // W2 resident ksteps 0..WR-1 -> registers
    s16x8 w2r[8][WR];
#pragma unroll
    for (int p = 0; p < 8; p++)
#pragma unroll
        for (int s = 0; s < WR; s++)
            w2r[p][s] = frag_from_W(W2, F_, 32 * s + 8 * lh, 16 * (8 * w + p) + lr);

    float b3r[2];
    float y_reg[2][4];
#pragma unroll
    for (int j = 0; j < 2; j++) {
        int c = 32 * w + 16 * j + lr;
        b3r[j] = b3[c];
#pragma unroll
        for (int i = 0; i < 4; i++)
            y_reg[j][i] = carry[(size_t)(rb + 4 * lh + i) * D_ + c];
    }
    __syncthreads();

    const f32x4 z4 = {0.f, 0.f, 0.f, 0.f};

    for (int t = 0; t < T_; t++) {
        // ---- prefetch pointwise inputs (hide under the whole step) ----
        float x1p[2][4], x2p[2][4], nvp[2][4];
#pragma unroll
        for (int j = 0; j < 2; j++) {
            int c = 32 * w + 16 * j + lr;
#pragma unroll
            for (int i = 0; i < 4; i++) {
                size_t bt = (size_t)(rb + 4 * lh + i) * T_ + t;
                x1p[j][i] = x[bt * (2 * D_) + c];
                x2p[j][i] = x[bt * (2 * D_) + D_ + c];
                nvp[j][i] = noise[bt * D_ + c];
            }
        }

        // ============ G1: z(160) -> h1 (all 512 cols; 8 tiles/wave, full K) ============
        {
            f32x4 a1[8];
#pragma unroll
            for (int p = 0; p < 8; p++) a1[p] = z4;
            if (t == 0) {
#pragma unroll
                for (int s = 0; s < 4; s++) {
                    s16x8 a = frag_from_f32(carry + (size_t)(rb + lr) * D_ + 32 * s + 8 * lh);
#pragma unroll
                    for (int p = 0; p < 8; p++) a1[p] = MFMA(a, w1r[p][s], a1[p], 0, 0, 0);
                }
            } else {
#pragma unroll
                for (int s = 0; s < 4; s++) {
                    s16x8 a = *(const s16x8*)&yxs[(s * 64 + l) * 8];
#pragma unroll
                    for (int p = 0; p < 8; p++) a1[p] = MFMA(a, w1r[p][s], a1[p], 0, 0, 0);
                }
            }
            {
                s16x8 a = frag_from_f32(ext + ((size_t)(rb + lr) * T_ + t) * E_ + 8 * lh);
#pragma unroll
                for (int p = 0; p < 8; p++) a1[p] = MFMA(a, w1r[p][4], a1[p], 0, 0, 0);
            }
            // h1 -> hx (A-frag layout; tile tl: k = 16*tl + lr)
#pragma unroll
            for (int p = 0; p < 8; p++) {
                const int tl = 8 * w + p;
#pragma unroll
                for (int i = 0; i < 4; i++) {
                    float v = tanhf(a1[p][i] + b1s[16 * tl + lr]);
                    float pv = __shfl_xor(v, 1);
                    if (!(l & 1))
                        hx[((tl >> 1) * 64 + 4 * lh + i + 16 * ((2 * tl + (lr >> 3)) & 3)) * 4
                           + ((lr & 7) >> 1)] = pack2(v, pv);
                }
            }
        }
        __syncthreads();                    // S1: h1 visible

        // ============ G2: h1(512) -> h2 (8 tiles/wave, full K; ksteps >= WR streamed) ============
        {
            f32x4 acc[8];
#pragma unroll
            for (int p = 0; p < 8; p++) acc[p] = z4;
            s16x8 stA[8], stB[8];
#pragma unroll
            for (int p = 0; p < 8; p++) stA[p] = ld_ws_frag(wsW2, 8 * w + p, WR, l);
#pragma unroll
            for (int p = 0; p < 8; p++) stB[p] = ld_ws_frag(wsW2, 8 * w + p, WR + 1, l);
#pragma unroll
            for (int s = 0; s < WR; s++) {
                s16x8 a = *(const s16x8*)&hxs[(s * 64 + l) * 8];
#pragma unroll
                for (int p = 0; p < 8; p++) acc[p] = MFMA(a, w2r[p][s], acc[p], 0, 0, 0);
            }
#pragma unroll
            for (int s = WR; s < 16; s++) {
                const int bs = (s - WR) & 1;
                s16x8 a = *(const s16x8*)&hxs[(s * 64 + l) * 8];
#pragma unroll
                for (int p = 0; p < 8; p++)
                    acc[p] = MFMA(a, bs ? stB[p] : stA[p], acc[p], 0, 0, 0);
                if (s + 2 < 16) {
#pragma unroll
                    for (int p = 0; p < 8; p++) {
                        s16x8 nf = ld_ws_frag(wsW2, 8 * w + p, s + 2, l);
                        if (bs) stB[p] = nf; else stA[p] = nf;
                    }
                }
            }
            __syncthreads();                // S2a: all h1 reads done
#pragma unroll
            for (int p = 0; p < 8; p++) {
                const int tl = 8 * w + p;
#pragma unroll
                for (int i = 0; i < 4; i++) {
                    float v = tanhf(acc[p][i] + b2s[16 * tl + lr]);
                    float pv = __shfl_xor(v, 1);
                    if (!(l & 1))
                        hx[((tl >> 1) * 64 + 4 * lh + i + 16 * ((2 * tl + (lr >> 3)) & 3)) * 4
                           + ((lr & 7) >> 1)] = pack2(v, pv);
                }
            }
        }
        __syncthreads();                    // S2b: h2 visible

        // ============ G3: h2(512) -> mu_phi (2 tiles/wave) + pointwise ============
        {
            f32x4 g3[2] = {z4, z4};
#pragma unroll
            for (int s = 0; s < 16; s++) {
                s16x8 a = *(const s16x8*)&hxs[(s * 64 + l) * 8];
#pragma unroll
                for (int j = 0; j < 2; j++)
                    g3[j] = MFMA(a, *(const s16x8*)&W3f[(((2 * w + j) * 16 + s) * 64 + l) * 8],
                                 g3[j], 0, 0, 0);
            }
#pragma unroll
            for (int j = 0; j < 2; j++) {
                const int c = 32 * w + 16 * j + lr;
                float yn4[4];
#pragma unroll
                for (int i = 0; i < 4; i++) {
                    float mu_phi = g3[j][i] + b3r[j];
                    int rg = rb + 4 * lh + i;
                    size_t bt = (size_t)rg * T_ + t;
                    float mu = (1.0f - ALPHA_F) * y_reg[j][i] + ALPHA_F * mu_phi + x1p[j][i];
                    float xv = x2p[j][i];
                    float sp = (xv > 0.f) ? (xv + log1pf(expf(-xv))) : log1pf(expf(xv));
                    float sd = SCALE_F * sp;
                    float yn = mu + sd * nvp[j][i];
                    mup_o[bt * D_ + c] = mu_phi;
                    mus_o[bt * D_ + c] = mu;
                    std_o[bt * D_ + c] = sd;
                    ys_o [bt * D_ + c] = yn;
                    y_reg[j][i] = yn;
                    yn4[i] = yn;
                    if (t == T_ - 1) yfin[(size_t)rg * D_ + c] = yn;
                }
                // y -> yx (A-frag layout for next step's G1)
#pragma unroll
                for (int i = 0; i < 4; i++) {
                    float pv = __shfl_xor(yn4[i], 1);
                    if (!(l & 1))
                        yx[(w * 64 + 4 * lh + i + 16 * ((2 * j + (lr >> 3)) & 3)) * 4
                           + ((lr & 7) >> 1)] = pack2(yn4[i], pv);
                }
            }
        }
        __syncthreads();                    // S3: yx visible; hx reads done for next G1
    }
}

extern "C" void kernel_launch(void* const* d_in, const int* in_sizes, int n_in,
                              void* d_out, int out_size, void* d_ws, size_t ws_size,
                              hipStream_t stream) {
    const float* carry = (const float*)d_in[0];
    const float* x     = (const float*)d_in[1];
    const float* ext   = (const float*)d_in[2];
    const float* noise = (const float*)d_in[3];
    const float* W1    = (const float*)d_in[4];
    const float* b1    = (const float*)d_in[5];
    const float* W2    = (const float*)d_in[6];
    const float* b2    = (const float*)d_in[7];
    const float* W3    = (const float*)d_in[8];
    const float* b3    = (const float*)d_in[9];
    float* out = (float*)d_out;
    unsigned* wsW2 = (unsigned*)d_ws;

    // One-time (per call) W2 -> bf16 frag image in ws (512 KB), then the scan.
    // Stream ordering makes the image visible to the scan kernel; no sync state anywhere.
    w2_convert_kernel<<<dim3(128), dim3(256), 0, stream>>>(W2, wsW2);
    sde_scan_kernel<<<dim3(16), dim3(256), 0, stream>>>(
        carry, x, ext, noise, W1, b1, W2, b2, W3, b3, out, wsW2);
}

// Round 12
// 2578.217 us; speedup vs baseline: 2.6302x; 2.6302x over previous
//
#include <hip/hip_runtime.h>
#include <cmath>

// Problem constants: B=256, T=256, D=128, E=32, F1=F2=512
#define B_   256
#define T_   256
#define D_   128
#define E_   32
#define F_   512
#define CB   16             // blocks per cluster
#define RC   16             // rows per cluster
#define NCL  16             // clusters
#define ALPHA_F 0.1f
#define SCALE_F 0.31622776601683794f   // sqrt(0.1)
#define WS_SYNC_BYTES 4096

typedef float f32x4 __attribute__((ext_vector_type(4)));
typedef short s16x8 __attribute__((ext_vector_type(8)));
#define MFMA __builtin_amdgcn_mfma_f32_16x16x32_bf16

// ---- bf16 helpers (RNE) ----
__device__ __forceinline__ unsigned short f2bf(float f) {
    unsigned u = __float_as_uint(f);
    return (unsigned short)((u + 0x7FFFu + ((u >> 16) & 1u)) >> 16);
}
__device__ __forceinline__ unsigned pack2(float lo, float hi) {
    return (unsigned)f2bf(lo) | ((unsigned)f2bf(hi) << 16);
}

// ---- coherent-point primitives (sc0 sc1: write-through / L1-L2-bypass loads) ----
__device__ __forceinline__ void st_coh_u32(unsigned* p, unsigned v) {
    __hip_atomic_store(p, v, __ATOMIC_RELAXED, __HIP_MEMORY_SCOPE_AGENT);
}
__device__ __forceinline__ unsigned long long ld_coh_u64(const unsigned long long* p) {
    return __hip_atomic_load(p, __ATOMIC_RELAXED, __HIP_MEMORY_SCOPE_AGENT);
}

// A-fragment (short8 = 8 bf16) from frag exchange buffer; lane l expects
// elems (row = l&15, k = 32*s + 8*(l>>4) + [0..8)). Buffer layout: u32 index
// (s*64 + lane')*4 + piece, lane' = r + 16*((k>>3)&3), piece = (k&7)>>1.
__device__ __forceinline__ s16x8 ld_frag(const unsigned* fb, int S, int l) {
    union { unsigned long long q[2]; s16x8 v; } u;
    const unsigned long long* p = (const unsigned long long*)(fb + (unsigned)(S * 64 + l) * 4u);
    u.q[0] = ld_coh_u64(p);
    u.q[1] = ld_coh_u64(p + 1);
    return u.v;
}

// A-fragment from 8 consecutive f32 in global memory (carry / ext paths)
__device__ __forceinline__ s16x8 frag_from_f32(const float* p) {
    float4 a = *(const float4*)p;
    float4 b = *(const float4*)(p + 4);
    union { unsigned q[4]; s16x8 v; } u;
    u.q[0] = pack2(a.x, a.y); u.q[1] = pack2(a.z, a.w);
    u.q[2] = pack2(b.x, b.y); u.q[3] = pack2(b.z, b.w);
    return u.v;
}

// ---- RMW-free cluster barrier (slot store + min-poll; R9-proven mechanism) ----
// Each wave drains its write-through stores (vmcnt 0); block-sync so ALL waves'
// exchange data is at the coherent point; thread 0 publishes its monotonic
// generation to its own slot (no fetch_add serialization) and min-polls the
// 16-slot cacheline until every block reached generation g. No reset, no leader.
__device__ __forceinline__ void cluster_barrier(unsigned* slots, int jb, unsigned g) {
    asm volatile("s_waitcnt vmcnt(0)" ::: "memory");
    __syncthreads();
    if (threadIdx.x == 0) {
        st_coh_u32(slots + jb, g);
        for (;;) {
            unsigned m = 0xFFFFFFFFu;
            const unsigned long long* p = (const unsigned long long*)slots;
#pragma unroll
            for (int i = 0; i < 8; i++) {
                unsigned long long v = ld_coh_u64(p + i);
                unsigned lo = (unsigned)v, hi = (unsigned)(v >> 32);
                m = m < lo ? m : lo;
                m = m < hi ? m : hi;
            }
            if (m >= g) break;
            __builtin_amdgcn_s_sleep(1);
        }
    }
    __syncthreads();
}

__global__ void __launch_bounds__(256, 1)
sde_scan_kernel(const float* __restrict__ carry, const float* __restrict__ x,
                const float* __restrict__ ext,   const float* __restrict__ noise,
                const float* __restrict__ W1,    const float* __restrict__ b1,
                const float* __restrict__ W2,    const float* __restrict__ b2,
                const float* __restrict__ W3,    const float* __restrict__ b3,
                float* __restrict__ out,         void* __restrict__ ws) {
    // bf16 weight fragments, converted once. B-frag: lane l = (c&15) + 16*((k>>3)&3), elem = k&7.
    __shared__ short W1f[2 * 5 * 64 * 8];    // 10 KB  (col-groups g=2, ksteps s=5)
    __shared__ short W2f[2 * 16 * 64 * 8];   // 32 KB
    __shared__ short W3f[16 * 64 * 8];       // 16 KB  (blocks j<8 only; cols 16j..16j+16)
    __shared__ float redb[8 * 64 * 4];       // 8 KB   (wave K-split combine)
    __shared__ float b1s[32], b2s[32], b3s[16];

    const int tid = threadIdx.x;
    const int bid = blockIdx.x;
    const int cl  = bid & 15;            // cluster
    const int jb  = bid >> 4;            // block-in-cluster 0..15
    const int rb  = cl * RC;             // global batch-row base
    const int cb  = jb * 32;             // F1/F2 col base

    const int w  = tid >> 6;             // wave 0..3
    const int l  = tid & 63;             // lane
    const int lr = l & 15;               // frag row (batch row) / output col
    const int lh = l >> 4;               // k-octet / row-quad

    unsigned* slots = (unsigned*)ws + cl * 64;   // 16 slots, 256B stride per cluster
    unsigned* yf  = (unsigned*)((char*)ws + WS_SYNC_BYTES) + cl * 1024;                  // 4 KB/cluster
    unsigned* h1f = (unsigned*)((char*)ws + WS_SYNC_BYTES + 65536) + cl * 4096;          // 16 KB/cluster
    unsigned* h2f = (unsigned*)((char*)ws + WS_SYNC_BYTES + 65536 + 262144) + cl * 4096; // 16 KB/cluster

    float* yfin  = out;
    float* ys_o  = out + B_ * D_;
    float* mup_o = ys_o  + (size_t)B_ * T_ * D_;
    float* mus_o = mup_o + (size_t)B_ * T_ * D_;
    float* std_o = mus_o + (size_t)B_ * T_ * D_;

    // ---- one-time weight conversion f32 -> bf16 frag layout ----
    for (int e4 = tid; e4 < 160 * 8; e4 += 256) {
        int k = e4 >> 3, c0 = (e4 & 7) << 2;
        float4 v = *(const float4*)(W1 + k * F_ + cb + c0);
        float vv[4] = {v.x, v.y, v.z, v.w};
#pragma unroll
        for (int m = 0; m < 4; m++) {
            int c = c0 + m;
            W1f[((((c >> 4) * 5 + (k >> 5)) * 64) + (c & 15) + 16 * ((k >> 3) & 3)) * 8 + (k & 7)] =
                (short)f2bf(vv[m]);
        }
    }
    for (int e4 = tid; e4 < 512 * 8; e4 += 256) {
        int k = e4 >> 3, c0 = (e4 & 7) << 2;
        float4 v = *(const float4*)(W2 + k * F_ + cb + c0);
        float vv[4] = {v.x, v.y, v.z, v.w};
#pragma unroll
        for (int m = 0; m < 4; m++) {
            int c = c0 + m;
            W2f[((((c >> 4) * 16 + (k >> 5)) * 64) + (c & 15) + 16 * ((k >> 3) & 3)) * 8 + (k & 7)] =
                (short)f2bf(vv[m]);
        }
    }
    if (jb < 8) {
        for (int e4 = tid; e4 < 512 * 4; e4 += 256) {
            int k = e4 >> 2, c0 = (e4 & 3) << 2;
            float4 v = *(const float4*)(W3 + k * D_ + 16 * jb + c0);
            float vv[4] = {v.x, v.y, v.z, v.w};
#pragma unroll
            for (int m = 0; m < 4; m++) {
                int c = c0 + m;
                W3f[(((k >> 5) * 64) + c + 16 * ((k >> 3) & 3)) * 8 + (k & 7)] = (short)f2bf(vv[m]);
            }
        }
    }
    if (tid < 32) { b1s[tid] = b1[cb + tid]; b2s[tid] = b2[cb + tid]; }
    if (tid < 16) { b3s[tid] = (jb < 8) ? b3[16 * jb + tid] : 0.f; }
    __syncthreads();

    // pointwise state (wave 0 of blocks jb<8): 4 rows (4*lh+i) x col cg3
    const int cg3 = 16 * jb + lr;
    float y_reg[4] = {0.f, 0.f, 0.f, 0.f};
    if (jb < 8 && w == 0) {
#pragma unroll
        for (int i = 0; i < 4; i++) y_reg[i] = carry[(size_t)(rb + 4 * lh + i) * D_ + cg3];
    }

    const f32x4 z4 = {0.f, 0.f, 0.f, 0.f};
    unsigned gbar = 0;

    for (int t = 0; t < T_; t++) {
        // prefetch pointwise inputs (hide under GEMMs)
        float x1p[4], x2p[4], nvp[4];
        if (jb < 8 && w == 0) {
#pragma unroll
            for (int i = 0; i < 4; i++) {
                size_t bt = (size_t)(rb + 4 * lh + i) * T_ + t;
                x1p[i] = x[bt * (2 * D_) + cg3];
                x2p[i] = x[bt * (2 * D_) + D_ + cg3];
                nvp[i] = noise[bt * D_ + cg3];
            }
        }

        // ================= GEMM1: z(160) -> h1 cols [32jb..32jb+32) =================
        // K-split: w0: s{0,1}, w1: s{2,3}, w2: s{4}=ext, w3 idle. Both col-groups per wave.
        if (w < 3) {
            f32x4 acc0 = z4, acc1 = z4;
            if (w == 2) {
                s16x8 a0 = frag_from_f32(ext + ((size_t)(rb + lr) * T_ + t) * E_ + 8 * lh);
                s16x8 b0 = *(const s16x8*)&W1f[((0 * 5 + 4) * 64 + l) * 8];
                s16x8 b1 = *(const s16x8*)&W1f[((1 * 5 + 4) * 64 + l) * 8];
                acc0 = MFMA(a0, b0, acc0, 0, 0, 0);
                acc1 = MFMA(a0, b1, acc1, 0, 0, 0);
            } else {
                int s0 = 2 * w, s1 = 2 * w + 1;
                s16x8 a0, a1;
                if (t == 0) {
                    a0 = frag_from_f32(carry + (size_t)(rb + lr) * D_ + 32 * s0 + 8 * lh);
                    a1 = frag_from_f32(carry + (size_t)(rb + lr) * D_ + 32 * s1 + 8 * lh);
                } else {
                    a0 = ld_frag(yf, s0, l);
                    a1 = ld_frag(yf, s1, l);
                }
                s16x8 b00 = *(const s16x8*)&W1f[((0 * 5 + s0) * 64 + l) * 8];
                s16x8 b01 = *(const s16x8*)&W1f[((0 * 5 + s1) * 64 + l) * 8];
                s16x8 b10 = *(const s16x8*)&W1f[((1 * 5 + s0) * 64 + l) * 8];
                s16x8 b11 = *(const s16x8*)&W1f[((1 * 5 + s1) * 64 + l) * 8];
                acc0 = MFMA(a0, b00, acc0, 0, 0, 0);
                acc0 = MFMA(a1, b01, acc0, 0, 0, 0);
                acc1 = MFMA(a0, b10, acc1, 0, 0, 0);
                acc1 = MFMA(a1, b11, acc1, 0, 0, 0);
            }
            *(f32x4*)&redb[((w * 2 + 0) * 64 + l) * 4] = acc0;
            *(f32x4*)&redb[((w * 2 + 1) * 64 + l) * 4] = acc1;
        }
        __syncthreads();
        if (w < 2) {   // wave w combines col-group g=w, applies bias+tanh, packs frags
            f32x4 s = *(const f32x4*)&redb[((0 * 2 + w) * 64 + l) * 4];
            f32x4 s1 = *(const f32x4*)&redb[((1 * 2 + w) * 64 + l) * 4];
            f32x4 s2 = *(const f32x4*)&redb[((2 * 2 + w) * 64 + l) * 4];
            int cl_ = 16 * w + lr;
            float bb = b1s[cl_];
#pragma unroll
            for (int i = 0; i < 4; i++) {
                float v = tanhf(s[i] + s1[i] + s2[i] + bb);
                float pv = __shfl_xor(v, 1);
                if (!(l & 1)) {
                    unsigned addr = (unsigned)(jb * 64 + 4 * lh + i + 16 * (cl_ >> 3)) * 4 + ((cl_ & 7) >> 1);
                    st_coh_u32(h1f + addr, pack2(v, pv));
                }
            }
        }
        cluster_barrier(slots, jb, ++gbar);

        // ================= GEMM2: h1(512) -> h2 cols [32jb..32jb+32) =================
        {
            s16x8 af[4];
#pragma unroll
            for (int q = 0; q < 4; q++) af[q] = ld_frag(h1f, 4 * w + q, l);
            f32x4 acc0 = z4, acc1 = z4;
#pragma unroll
            for (int q = 0; q < 4; q++) {
                int s = 4 * w + q;
                s16x8 b0 = *(const s16x8*)&W2f[((0 * 16 + s) * 64 + l) * 8];
                s16x8 b1 = *(const s16x8*)&W2f[((1 * 16 + s) * 64 + l) * 8];
                acc0 = MFMA(af[q], b0, acc0, 0, 0, 0);
                acc1 = MFMA(af[q], b1, acc1, 0, 0, 0);
            }
            *(f32x4*)&redb[((w * 2 + 0) * 64 + l) * 4] = acc0;
            *(f32x4*)&redb[((w * 2 + 1) * 64 + l) * 4] = acc1;
        }
        __syncthreads();
        if (w < 2) {
            f32x4 s0 = *(const f32x4*)&redb[((0 * 2 + w) * 64 + l) * 4];
            f32x4 s1 = *(const f32x4*)&redb[((1 * 2 + w) * 64 + l) * 4];
            f32x4 s2 = *(const f32x4*)&redb[((2 * 2 + w) * 64 + l) * 4];
            f32x4 s3 = *(const f32x4*)&redb[((3 * 2 + w) * 64 + l) * 4];
            int cl_ = 16 * w + lr;
            float bb = b2s[cl_];
#pragma unroll
            for (int i = 0; i < 4; i++) {
                float v = tanhf(s0[i] + s1[i] + s2[i] + s3[i] + bb);
                float pv = __shfl_xor(v, 1);
                if (!(l & 1)) {
                    unsigned addr = (unsigned)(jb * 64 + 4 * lh + i + 16 * (cl_ >> 3)) * 4 + ((cl_ & 7) >> 1);
                    st_coh_u32(h2f + addr, pack2(v, pv));
                }
            }
        }
        cluster_barrier(slots, jb, ++gbar);

        // ========== GEMM3: h2(512) -> mu_phi cols [16jb..16jb+16)  (blocks jb<8) ==========
        if (jb < 8) {
            s16x8 af[4];
#pragma unroll
            for (int q = 0; q < 4; q++) af[q] = ld_frag(h2f, 4 * w + q, l);
            f32x4 acc = z4;
#pragma unroll
            for (int q = 0; q < 4; q++) {
                s16x8 b0 = *(const s16x8*)&W3f[((4 * w + q) * 64 + l) * 8];
                acc = MFMA(af[q], b0, acc, 0, 0, 0);
            }
            if (w != 0) *(f32x4*)&redb[(w * 64 + l) * 4] = acc;
            __syncthreads();
            if (w == 0) {
                f32x4 p1 = *(const f32x4*)&redb[(1 * 64 + l) * 4];
                f32x4 p2 = *(const f32x4*)&redb[(2 * 64 + l) * 4];
                f32x4 p3 = *(const f32x4*)&redb[(3 * 64 + l) * 4];
                float bb = b3s[lr];
                float yn4[4];
#pragma unroll
                for (int i = 0; i < 4; i++) {
                    float mu_phi = acc[i] + p1[i] + p2[i] + p3[i] + bb;
                    int rg = rb + 4 * lh + i;
                    size_t bt = (size_t)rg * T_ + t;
                    float mu = (1.0f - ALPHA_F) * y_reg[i] + ALPHA_F * mu_phi + x1p[i];
                    float sp = (x2p[i] > 0.f) ? (x2p[i] + log1pf(expf(-x2p[i]))) : log1pf(expf(x2p[i]));
                    float sd = SCALE_F * sp;
                    float yn = mu + sd * nvp[i];
                    mup_o[bt * D_ + cg3] = mu_phi;
                    mus_o[bt * D_ + cg3] = mu;
                    std_o[bt * D_ + cg3] = sd;
                    ys_o [bt * D_ + cg3] = yn;
                    y_reg[i] = yn;
                    yn4[i] = yn;
                    if (t == T_ - 1) yfin[(size_t)rg * D_ + cg3] = yn;
                }
                // y-frag exchange for next step's GEMM1 (k = 16*jb + lr)
#pragma unroll
                for (int i = 0; i < 4; i++) {
                    float pv = __shfl_xor(yn4[i], 1);
                    if (!(l & 1)) {
                        int k = 16 * jb + lr;   // even
                        unsigned addr = (unsigned)((k >> 5) * 64 + 4 * lh + i + 16 * ((k >> 3) & 3)) * 4
                                        + ((lr & 7) >> 1);
                        st_coh_u32(yf + addr, pack2(yn4[i], pv));
                    }
                }
            }
        }
        cluster_barrier(slots, jb, ++gbar);
    }
}

extern "C" void kernel_launch(void* const* d_in, const int* in_sizes, int n_in,
                              void* d_out, int out_size, void* d_ws, size_t ws_size,
                              hipStream_t stream) {
    const float* carry = (const float*)d_in[0];
    const float* x     = (const float*)d_in[1];
    const float* ext   = (const float*)d_in[2];
    const float* noise = (const float*)d_in[3];
    const float* W1    = (const float*)d_in[4];
    const float* b1    = (const float*)d_in[5];
    const float* W2    = (const float*)d_in[6];
    const float* b2    = (const float*)d_in[7];
    const float* W3    = (const float*)d_in[8];
    const float* b3    = (const float*)d_in[9];
    float* out = (float*)d_out;
    void* ws   = d_ws;

    // Zero only the barrier slot region (generations are monotonic within a call).
    hipMemsetAsync(d_ws, 0, WS_SYNC_BYTES, stream);

    sde_scan_kernel<<<dim3(256), dim3(256), 0, stream>>>(
        carry, x, ext, noise, W1, b1, W2, b2, W3, b3, out, ws);
}